// Round 2
// baseline (4000.937 us; speedup 1.0000x reference)
//
#include <hip/hip_runtime.h>

typedef unsigned short u16;
typedef __attribute__((ext_vector_type(4))) float f32x4;
typedef __attribute__((ext_vector_type(8))) short bf16x8;
#define MFMA16(a,b,c) __builtin_amdgcn_mfma_f32_16x16x32_bf16((a),(b),(c),0,0,0)

template<int N> struct ic { static constexpr int v = N; };

__device__ __forceinline__ u16 f2bf(float f){
  unsigned int u = __float_as_uint(f);
  u += 0x7FFFu + ((u >> 16) & 1u);
  return (u16)(u >> 16);
}
__device__ __forceinline__ float bf2f(u16 h){
  return __uint_as_float(((unsigned int)h) << 16);
}
__device__ __forceinline__ float sigmoid_f(float x){
  x = fminf(fmaxf(x, -30.f), 30.f);
  return __fdividef(1.f, 1.f + __expf(-x));
}
__device__ __forceinline__ float tanh_f(float x){
  x = fminf(fmaxf(x, -15.f), 15.f);
  float e = __expf(-2.f * x);
  return __fdividef(1.f - e, 1.f + e);
}

// fp32 -> bf16 weight conversion (grid-stride)
__global__ void cvt_bf16_kernel(const float* __restrict__ in, u16* __restrict__ out, int n){
  int i = blockIdx.x * 256 + threadIdx.x;
  int stride = gridDim.x * 256;
  for (; i < n; i += stride) out[i] = f2bf(in[i]);
}

// Block-wide LN stats for R rows of a [R x 256] LDS buffer (stride 256).
template<int R>
__device__ __forceinline__ void ln_stats_rows(const float* __restrict__ O,
                                              float* __restrict__ mean_s,
                                              float* __restrict__ rstd_s){
  const int tid  = threadIdx.x;
  const int wave = tid >> 6, lane = tid & 63;
  constexpr int RW = R / 4;
  #pragma unroll
  for (int rr = 0; rr < RW; rr++){
    const int r = wave * RW + rr;
    float s = 0.f, q = 0.f;
    #pragma unroll
    for (int i = lane; i < 256; i += 64){ float v = O[r*256 + i]; s += v; q += v*v; }
    #pragma unroll
    for (int off = 32; off; off >>= 1){ s += __shfl_down(s, off); q += __shfl_down(q, off); }
    if (lane == 0){
      float m   = s * (1.f/256.f);
      float var = q * (1.f/256.f) - m*m;
      mean_s[r] = m;
      rstd_s[r] = rsqrtf(fmaxf(var, 0.f) + 1e-5f);
    }
  }
}

// ---------------------------------------------------------------------------
// MFMA-based fused per-edge kernel, v3:
//   TM edges/block, 512 threads (8 waves), wave w owns output cols
//   [w*32, w*32+32), processed as two sequential 16-col phases.
//   h double-buffered in LDS.  x tile: XBUFS==2 -> double-buffered (1 barrier
//   per step); XBUFS==1 -> single-buffered (2 barriers/step) to fit
//   LDS <= 80 KB so TWO blocks can be resident per CU (the round-1 kernel was
//   LDS-locked to 1 block/CU -> every barrier drained the whole CU).
//   Epilogue nodef staging goes into the free h buffer (XBUFS==1) or xb
//   (XBUFS==2); LN scratch aliases dead LDS.
// ---------------------------------------------------------------------------
template<int TM, int DIN, int NFD, int XBUFS>
__global__ __launch_bounds__(512, 4)
void gru_mfma_kernel(int E,
    const float* __restrict__ x,        // [E, 8, DIN] fp32
    const float* __restrict__ nodef,    // [*, NFD] fp32
    const int*   __restrict__ src,
    const int*   __restrict__ dst,
    const float* __restrict__ hist,     // [*, 256] fp32
    const u16*   __restrict__ Wih,      // [768, DIN] bf16
    const u16*   __restrict__ Whh,      // [768, 256] bf16
    const float* __restrict__ bih,
    const float* __restrict__ bhh,
    const u16*   __restrict__ phiW,     // [256, NFD+256] bf16
    const float* __restrict__ phib,
    const float* __restrict__ phig,
    const float* __restrict__ phibeta,
    float* __restrict__ delta)          // [*, 256] fp32, pre-zeroed
{
  constexpr int HP   = 264;             // h row stride (+8: 16B-aligned rows)
  constexpr int XP   = DIN + 8;         // x row stride
  constexpr int NP   = NFD + 8;         // nodef row stride
  constexpr int KP   = NFD + 256;       // phi K
  constexpr int MT   = TM / 16;         // m-tiles
  constexpr int NF4  = (TM * DIN) / 2048;  // float4/thread per x stage
  constexpr int HBUF = TM * HP;
  constexpr int XBUF = TM * XP;

  __shared__ __align__(16) u16 hb[2 * HBUF];
  __shared__ __align__(16) u16 xb[XBUFS * XBUF];
  __shared__ int srcs_s[TM], dsts_s[TM];

  const int tid  = threadIdx.x;
  const int wave = tid >> 6, lane = tid & 63;
  const int quad = lane >> 4, ln15 = lane & 15;
  const int qoff = quad * 8;
  const int cbase = wave * 32;
  const int e0   = blockIdx.x * TM;

  if (tid < TM){
    int e  = e0 + tid;
    int ec = (e < E) ? e : (E - 1);
    srcs_s[tid] = src[ec];
    dsts_s[tid] = dst[ec];
  }

  int cn[2]; float brc[2], bzc[2], bnic[2], bnhc[2], pb[2], gg[2], gb[2];
  #pragma unroll
  for (int nt = 0; nt < 2; nt++){
    int c   = cbase + nt * 16 + ln15;
    cn[nt]  = c;
    brc[nt]  = bih[c]       + bhh[c];
    bzc[nt]  = bih[256 + c] + bhh[256 + c];
    bnic[nt] = bih[512 + c];
    bnhc[nt] = bhh[512 + c];
    pb[nt]   = phib[c];
    gg[nt]   = phig[c];
    gb[nt]   = phibeta[c];
  }

  // stage x_0 into buffer 0
  #pragma unroll
  for (int j = 0; j < NF4; j++){
    int i4 = tid + j * 512;
    int e  = i4 / (DIN / 4);
    int k4 = (i4 % (DIN / 4)) * 4;
    int ge = (e0 + e < E) ? (e0 + e) : (E - 1);
    float4 v = *(const float4*)(x + (size_t)ge * (8 * DIN) + k4);
    ushort4 u;
    u.x = f2bf(v.x); u.y = f2bf(v.y); u.z = f2bf(v.z); u.w = f2bf(v.w);
    *(ushort4*)(xb + e * XP + k4) = u;
  }
  __syncthreads();

  float hs[2][MT][4];
  #pragma unroll
  for (int nt = 0; nt < 2; nt++)
    #pragma unroll
    for (int mt = 0; mt < MT; mt++)
      #pragma unroll
      for (int q = 0; q < 4; q++) hs[nt][mt][q] = 0.f;

  const f32x4 zero4 = {0.f, 0.f, 0.f, 0.f};

  #pragma unroll 1
  for (int t = 0; t < 8; t++){
    const u16* rd = hb + ((t & 1) ^ 1) * HBUF;
    u16*       wr = hb + (t & 1) * HBUF;
    const u16* xr = xb + ((XBUFS == 2) ? (t & 1) * XBUF : 0);

    // prefetch x_{t+1} into registers (HBM latency hidden under this step)
    float4 xpre[NF4];
    if (t < 7){
      #pragma unroll
      for (int j = 0; j < NF4; j++){
        int i4 = tid + j * 512;
        int e  = i4 / (DIN / 4);
        int k4 = (i4 % (DIN / 4)) * 4;
        int ge = (e0 + e < E) ? (e0 + e) : (E - 1);
        xpre[j] = *(const float4*)(x + (size_t)ge * (8 * DIN) + (size_t)(t + 1) * DIN + k4);
      }
    }

    auto phase = [&](auto ntc){
      constexpr int NT = decltype(ntc)::v;    // compile-time phase: static idx
      const int c = cn[NT];
      f32x4 aR[MT], aZ[MT], aNI[MT], aNH[MT];
      #pragma unroll
      for (int mt = 0; mt < MT; mt++){
        aR[mt] = zero4; aZ[mt] = zero4; aNI[mt] = zero4; aNH[mt] = zero4;
      }
      if (t > 0){
        #pragma unroll
        for (int kt = 0; kt < 8; kt++){
          bf16x8 a[MT];
          #pragma unroll
          for (int mt = 0; mt < MT; mt++)
            a[mt] = *(const bf16x8*)(rd + (mt*16 + ln15) * HP + kt * 32 + qoff);
          const u16* bp = Whh + (size_t)c * 256 + kt * 32 + qoff;
          bf16x8 br = *(const bf16x8*)(bp);
          bf16x8 bz = *(const bf16x8*)(bp + 256 * 256);
          bf16x8 bn = *(const bf16x8*)(bp + 512 * 256);
          #pragma unroll
          for (int mt = 0; mt < MT; mt++){
            aR[mt]  = MFMA16(a[mt], br, aR[mt]);
            aZ[mt]  = MFMA16(a[mt], bz, aZ[mt]);
            aNH[mt] = MFMA16(a[mt], bn, aNH[mt]);
          }
        }
      }
      #pragma unroll
      for (int kt = 0; kt < DIN / 32; kt++){
        bf16x8 a[MT];
        #pragma unroll
        for (int mt = 0; mt < MT; mt++)
          a[mt] = *(const bf16x8*)(xr + (mt*16 + ln15) * XP + kt * 32 + qoff);
        const u16* bp = Wih + (size_t)c * DIN + kt * 32 + qoff;
        bf16x8 br = *(const bf16x8*)(bp);
        bf16x8 bz = *(const bf16x8*)(bp + 256 * DIN);
        bf16x8 bn = *(const bf16x8*)(bp + 512 * DIN);
        #pragma unroll
        for (int mt = 0; mt < MT; mt++){
          aR[mt]  = MFMA16(a[mt], br, aR[mt]);
          aZ[mt]  = MFMA16(a[mt], bz, aZ[mt]);
          aNI[mt] = MFMA16(a[mt], bn, aNI[mt]);
        }
      }
      // gates + h update (own 16 cols of this phase)
      #pragma unroll
      for (int mt = 0; mt < MT; mt++){
        #pragma unroll
        for (int q = 0; q < 4; q++){
          const int e = mt * 16 + quad * 4 + q;
          float r = sigmoid_f(aR[mt][q] + brc[NT]);
          float z = sigmoid_f(aZ[mt][q] + bzc[NT]);
          float n = tanh_f(aNI[mt][q] + bnic[NT] + r * (aNH[mt][q] + bnhc[NT]));
          float hold = (t > 0) ? bf2f(rd[e * HP + c]) : 0.f;
          float hnew = (1.f - z) * n + z * hold;
          hs[NT][mt][q] += hnew;
          if (t < 7) wr[e * HP + c] = f2bf(hnew);
        }
      }
    };
    phase(ic<0>());
    phase(ic<1>());

    if (XBUFS == 1){
      __syncthreads();                       // all x_t / h reads done
      if (t < 7){
        #pragma unroll
        for (int j = 0; j < NF4; j++){
          int i4 = tid + j * 512;
          int e  = i4 / (DIN / 4);
          int k4 = (i4 % (DIN / 4)) * 4;
          ushort4 u;
          u.x = f2bf(xpre[j].x); u.y = f2bf(xpre[j].y);
          u.z = f2bf(xpre[j].z); u.w = f2bf(xpre[j].w);
          *(ushort4*)(xb + e * XP + k4) = u;
        }
        __syncthreads();                     // x_{t+1} visible
      }
    } else {
      if (t < 7){
        u16* xw = xb + (((t + 1) & 1)) * XBUF;
        #pragma unroll
        for (int j = 0; j < NF4; j++){
          int i4 = tid + j * 512;
          int e  = i4 / (DIN / 4);
          int k4 = (i4 % (DIN / 4)) * 4;
          ushort4 u;
          u.x = f2bf(xpre[j].x); u.y = f2bf(xpre[j].y);
          u.z = f2bf(xpre[j].z); u.w = f2bf(xpre[j].w);
          *(ushort4*)(xw + e * XP + k4) = u;
        }
      }
      __syncthreads();
    }
  }

  // emb = mean(h) -> hb buf0; stage nodef[src] into free LDS:
  //   XBUFS==1: h buf1 (dead since t=6); XBUFS==2: xb buf0 (dead since t=6).
  u16* nb = (XBUFS == 1) ? (hb + HBUF) : xb;
  {
    u16* eb = hb;
    #pragma unroll
    for (int nt = 0; nt < 2; nt++)
      #pragma unroll
      for (int mt = 0; mt < MT; mt++)
        #pragma unroll
        for (int q = 0; q < 4; q++){
          const int e = mt * 16 + quad * 4 + q;
          eb[e * HP + cn[nt]] = f2bf(hs[nt][mt][q] * 0.125f);
        }
    constexpr int R4 = NFD / 4;
    for (int i = tid; i < TM * R4; i += 512){
      int e  = i / R4;
      int k4 = (i - e * R4) * 4;
      const float4 v = *(const float4*)(nodef + (size_t)srcs_s[e] * NFD + k4);
      ushort4 u;
      u.x = f2bf(v.x); u.y = f2bf(v.y); u.z = f2bf(v.z); u.w = f2bf(v.w);
      *(ushort4*)(nb + e * NP + k4) = u;
    }
  }
  __syncthreads();

  // phi GEMM: K = NFD (nb) + 256 (emb in hb buf0)
  f32x4 P[2][MT];
  #pragma unroll
  for (int nt = 0; nt < 2; nt++)
    #pragma unroll
    for (int mt = 0; mt < MT; mt++) P[nt][mt] = zero4;

  #pragma unroll
  for (int kt = 0; kt < NFD / 32; kt++){
    bf16x8 a[MT];
    #pragma unroll
    for (int mt = 0; mt < MT; mt++)
      a[mt] = *(const bf16x8*)(nb + (mt*16 + ln15) * NP + kt * 32 + qoff);
    #pragma unroll
    for (int nt = 0; nt < 2; nt++){
      const u16* bp = phiW + (size_t)cn[nt] * KP + kt * 32 + qoff;
      bf16x8 b = *(const bf16x8*)(bp);
      #pragma unroll
      for (int mt = 0; mt < MT; mt++) P[nt][mt] = MFMA16(a[mt], b, P[nt][mt]);
    }
  }
  #pragma unroll
  for (int kt = 0; kt < 8; kt++){
    bf16x8 a[MT];
    #pragma unroll
    for (int mt = 0; mt < MT; mt++)
      a[mt] = *(const bf16x8*)(hb + (mt*16 + ln15) * HP + kt * 32 + qoff);
    #pragma unroll
    for (int nt = 0; nt < 2; nt++){
      const u16* bp = phiW + (size_t)cn[nt] * KP + NFD + kt * 32 + qoff;
      bf16x8 b = *(const bf16x8*)(bp);
      #pragma unroll
      for (int mt = 0; mt < MT; mt++) P[nt][mt] = MFMA16(a[mt], b, P[nt][mt]);
    }
  }

  // LN scratch aliases LDS that is dead in the epilogue:
  //   XBUFS==1: xb (phi reads hb only); XBUFS==2: hb buf1.
  float* sums_s = (float*)((XBUFS == 1) ? (void*)xb : (void*)(hb + HBUF));
  float* sqs_s  = sums_s + 8 * TM;
  float* mean_s = sqs_s  + 8 * TM;
  float* rstd_s = mean_s + TM;

  // bias + LN stats: shuffle over 16 lanes (32 cols/wave) -> cross-wave via LDS
  float sl[MT][4], sq_[MT][4];
  #pragma unroll
  for (int mt = 0; mt < MT; mt++)
    #pragma unroll
    for (int q = 0; q < 4; q++){
      float v0 = P[0][mt][q] + pb[0];
      float v1 = P[1][mt][q] + pb[1];
      P[0][mt][q] = v0; P[1][mt][q] = v1;
      sl[mt][q]  = v0 + v1;
      sq_[mt][q] = v0 * v0 + v1 * v1;
    }
  #pragma unroll
  for (int off = 1; off < 16; off <<= 1){
    #pragma unroll
    for (int mt = 0; mt < MT; mt++)
      #pragma unroll
      for (int q = 0; q < 4; q++){
        sl[mt][q]  += __shfl_xor(sl[mt][q], off);
        sq_[mt][q] += __shfl_xor(sq_[mt][q], off);
      }
  }
  if (ln15 == 0){
    #pragma unroll
    for (int mt = 0; mt < MT; mt++)
      #pragma unroll
      for (int q = 0; q < 4; q++){
        int row = mt * 16 + quad * 4 + q;
        sums_s[wave * TM + row] = sl[mt][q];
        sqs_s[wave * TM + row]  = sq_[mt][q];
      }
  }
  __syncthreads();
  if (tid < TM){
    float m = 0.f, qq = 0.f;
    #pragma unroll
    for (int w = 0; w < 8; w++){ m += sums_s[w * TM + tid]; qq += sqs_s[w * TM + tid]; }
    m  *= (1.f / 256.f);
    qq *= (1.f / 256.f);
    mean_s[tid] = m;
    rstd_s[tid] = rsqrtf(fmaxf(qq - m * m, 0.f) + 1e-5f);
  }
  __syncthreads();

  // y = relu(LN(...)), msg = relu(y - hist[src]) -> atomic scatter into delta[dst]
  #pragma unroll
  for (int nt = 0; nt < 2; nt++){
    const int c = cn[nt];
    #pragma unroll
    for (int mt = 0; mt < MT; mt++)
      #pragma unroll
      for (int q = 0; q < 4; q++){
        const int e  = mt * 16 + quad * 4 + q;
        const int ge = e0 + e;
        float y = (P[nt][mt][q] - mean_s[e]) * rstd_s[e] * gg[nt] + gb[nt];
        y = fmaxf(y, 0.f);
        float mv = y - hist[(size_t)srcs_s[e] * 256 + c];
        if (ge < E && mv > 0.f)
          atomicAdd(delta + (size_t)dsts_s[e] * 256 + c, mv);
      }
  }
}

// ---------------------------------------------------------------------------
// self-SLNN: out = relu(LN(feat[nid] @ W[:, WS-K:].T + b)); optional
// out2 = out - hist[nid].
// ---------------------------------------------------------------------------
template<int K, int WS>
__global__ __launch_bounds__(256)
void self_slnn_kernel(int N,
    const float* __restrict__ feat,
    const int*   __restrict__ nid,
    const float* __restrict__ W,
    const float* __restrict__ b,
    const float* __restrict__ g,
    const float* __restrict__ beta,
    const float* __restrict__ hist,
    float* __restrict__ out,
    float* __restrict__ out2)
{
  constexpr int R = 8;
  __shared__ float X[R*K];
  __shared__ float O[R*256];
  __shared__ float mean_s[R], rstd_s[R];
  __shared__ int   nids[R];
  const int tid = threadIdx.x;
  const int n0  = blockIdx.x * R;
  if (tid < R) nids[tid] = (n0 + tid < N) ? nid[n0 + tid] : 0;
  __syncthreads();
  for (int i = tid; i < R*K; i += 256){
    int r = i / K, k = i - r*K;
    X[i] = feat[(size_t)nids[r]*K + k];
  }
  __syncthreads();
  const int c = tid;
  const float* Wc = W + (size_t)c*WS + (WS - K);
  float acc[R];
  const float bc0 = b[c];
  #pragma unroll
  for (int r = 0; r < R; r++) acc[r] = bc0;
  #pragma unroll 1
  for (int k = 0; k < K; k += 4){
    float4 w = *(const float4*)(Wc + k);
    #pragma unroll
    for (int r = 0; r < R; r++){
      float4 xv = *(const float4*)(X + r*K + k);
      acc[r] += w.x*xv.x + w.y*xv.y + w.z*xv.z + w.w*xv.w;
    }
  }
  #pragma unroll
  for (int r = 0; r < R; r++) O[r*256 + c] = acc[r];
  __syncthreads();
  ln_stats_rows<R>(O, mean_s, rstd_s);
  __syncthreads();
  const float gc = g[c], bc = beta[c];
  #pragma unroll
  for (int r = 0; r < R; r++){
    int n = n0 + r;
    if (n < N){
      float y = fmaxf((acc[r] - mean_s[r]) * rstd_s[r] * gc + bc, 0.f);
      out[(size_t)n*256 + c] = y;
      if (out2) out2[(size_t)n*256 + c] = y - hist[(size_t)nids[r]*256 + c];
    }
  }
}

// ---------------------------------------------------------------------------
// compose-SLNN: X = [ (delta - selfA)*subg (+ agg*normv) | selfB ]  (K=512)
// ---------------------------------------------------------------------------
__global__ __launch_bounds__(256)
void compose_slnn_kernel(int N,
    const float* __restrict__ delta,
    const float* __restrict__ selfA,
    const float* __restrict__ selfB,
    const float* __restrict__ subg,
    const float* __restrict__ agg,
    const float* __restrict__ normv,
    const float* __restrict__ W,     // [256, 512]
    const float* __restrict__ b,
    const float* __restrict__ g,
    const float* __restrict__ beta,
    float* __restrict__ out)
{
  constexpr int R = 8;
  __shared__ float X[R*512];
  __shared__ float O[R*256];
  __shared__ float mean_s[R], rstd_s[R];
  const int tid = threadIdx.x;
  const int n0  = blockIdx.x * R;
  for (int i = tid; i < R*512; i += 256){
    int r = i >> 9, k = i & 511;
    int n = n0 + r;
    float v = 0.f;
    if (n < N){
      if (k < 256){
        v = (delta[(size_t)n*256 + k] - selfA[(size_t)n*256 + k]) * subg[n];
        if (agg) v += agg[(size_t)n*256 + k] * normv[n];
      } else {
        v = selfB[(size_t)n*256 + (k - 256)];
      }
    }
    X[i] = v;
  }
  __syncthreads();
  const int c = tid;
  const float* Wc = W + (size_t)c*512;
  float acc[R];
  const float bc0 = b[c];
  #pragma unroll
  for (int r = 0; r < R; r++) acc[r] = bc0;
  #pragma unroll 1
  for (int k = 0; k < 512; k += 4){
    float4 w = *(const float4*)(Wc + k);
    #pragma unroll
    for (int r = 0; r < R; r++){
      float4 xv = *(const float4*)(X + r*512 + k);
      acc[r] += w.x*xv.x + w.y*xv.y + w.z*xv.z + w.w*xv.w;
    }
  }
  #pragma unroll
  for (int r = 0; r < R; r++) O[r*256 + c] = acc[r];
  __syncthreads();
  ln_stats_rows<R>(O, mean_s, rstd_s);
  __syncthreads();
  const float gc = g[c], bc = beta[c];
  #pragma unroll
  for (int r = 0; r < R; r++){
    int n = n0 + r;
    if (n < N)
      out[(size_t)n*256 + c] = fmaxf((acc[r] - mean_s[r]) * rstd_s[r] * gc + bc, 0.f);
  }
}

// ---------------------------------------------------------------------------
// readout: logit = (h2 @ fc1.T + b1) @ fc2.T + b2
// ---------------------------------------------------------------------------
__global__ __launch_bounds__(256)
void readout_kernel(int N,
    const float* __restrict__ h2,
    const float* __restrict__ W1,  // [512, 256]
    const float* __restrict__ b1,
    const float* __restrict__ W2,  // [16, 512]
    const float* __restrict__ b2,
    float* __restrict__ out)
{
  constexpr int R = 8;
  __shared__ float X[R*256];
  __shared__ float T[R*512];
  const int tid = threadIdx.x;
  const int n0  = blockIdx.x * R;
  for (int i = tid; i < R*256; i += 256){
    int r = i >> 8, k = i & 255;
    int n = n0 + r;
    X[i] = (n < N) ? h2[(size_t)n*256 + k] : 0.f;
  }
  __syncthreads();
  const int c = tid;
  const float* Wa = W1 + (size_t)c*256;
  const float* Wb = W1 + (size_t)(c+256)*256;
  float acca[R], accb[R];
  const float ba = b1[c], bb = b1[c+256];
  #pragma unroll
  for (int r = 0; r < R; r++){ acca[r] = ba; accb[r] = bb; }
  #pragma unroll 1
  for (int k = 0; k < 256; k += 4){
    float4 wa = *(const float4*)(Wa + k);
    float4 wb = *(const float4*)(Wb + k);
    #pragma unroll
    for (int r = 0; r < R; r++){
      float4 xv = *(const float4*)(X + r*256 + k);
      acca[r] += wa.x*xv.x + wa.y*xv.y + wa.z*xv.z + wa.w*xv.w;
      accb[r] += wb.x*xv.x + wb.y*xv.y + wb.z*xv.z + wb.w*xv.w;
    }
  }
  #pragma unroll
  for (int r = 0; r < R; r++){ T[r*512 + c] = acca[r]; T[r*512 + 256 + c] = accb[r]; }
  __syncthreads();
  if (tid < R*16){
    int r = tid >> 4, o = tid & 15;
    int n = n0 + r;
    if (n < N){
      float s = b2[o];
      const float* w  = W2 + (size_t)o*512;
      const float* tr = T + r*512;
      #pragma unroll 4
      for (int k = 0; k < 512; k++) s += tr[k]*w[k];
      out[(size_t)n*16 + o] = s;
    }
  }
}

// ---------------------------------------------------------------------------
extern "C" void kernel_launch(void* const* d_in, const int* in_sizes, int n_in,
                              void* d_out, int out_size, void* d_ws, size_t ws_size,
                              hipStream_t stream) {
  const float* nf     = (const float*)d_in[0];
  const float* x0     = (const float*)d_in[1];
  const float* x1     = (const float*)d_in[2];
  const float* hist0  = (const float*)d_in[3];
  const float* hist1  = (const float*)d_in[4];
  const float* aggh1  = (const float*)d_in[5];
  const float* subg1  = (const float*)d_in[6];
  const float* subg2  = (const float*)d_in[7];
  const float* norm2  = (const float*)d_in[8];
  const int*   src0   = (const int*)d_in[9];
  const int*   dst0   = (const int*)d_in[10];
  const int*   src1   = (const int*)d_in[11];
  const int*   dst1   = (const int*)d_in[12];
  const int*   nid0   = (const int*)d_in[13];
  const int*   nid1   = (const int*)d_in[14];
  const float* g0Wih  = (const float*)d_in[15];
  const float* g0Whh  = (const float*)d_in[16];
  const float* g0bih  = (const float*)d_in[17];
  const float* g0bhh  = (const float*)d_in[18];
  const float* g1Wih  = (const float*)d_in[19];
  const float* g1Whh  = (const float*)d_in[20];
  const float* g1bih  = (const float*)d_in[21];
  const float* g1bhh  = (const float*)d_in[22];
  const float* phi0W  = (const float*)d_in[23];
  const float* phi0b  = (const float*)d_in[24];
  const float* phi0g  = (const float*)d_in[25];
  const float* phi0be = (const float*)d_in[26];
  const float* phi1W  = (const float*)d_in[27];
  const float* phi1b  = (const float*)d_in[28];
  const float* phi1g  = (const float*)d_in[29];
  const float* phi1be = (const float*)d_in[30];
  const float* nu0W   = (const float*)d_in[31];
  const float* nu0b   = (const float*)d_in[32];
  const float* nu0g   = (const float*)d_in[33];
  const float* nu0be  = (const float*)d_in[34];
  const float* nu1W   = (const float*)d_in[35];
  const float* nu1b   = (const float*)d_in[36];
  const float* nu1g   = (const float*)d_in[37];
  const float* nu1be  = (const float*)d_in[38];
  const float* fc1W   = (const float*)d_in[39];
  const float* fc1b   = (const float*)d_in[40];
  const float* fc2W   = (const float*)d_in[41];
  const float* fc2b   = (const float*)d_in[42];

  const int E0 = in_sizes[9];
  const int E1 = in_sizes[11];
  const int N1 = in_sizes[13];
  const int N2 = in_sizes[14];

  float* ws     = (float*)d_ws;
  float* delta0 = ws;
  float* selfh0 = delta0 + (size_t)N1*256;
  float* h1p    = selfh0 + (size_t)N1*256;
  float* delta1 = h1p    + (size_t)N1*256;
  float* selfh1 = delta1 + (size_t)N2*256;
  float* selfd1 = selfh1 + (size_t)N2*256;
  float* h2p    = selfd1 + (size_t)N2*256;

  // bf16 weight copies (converted every call; ws is re-poisoned by harness)
  u16* wbf       = (u16*)(h2p + (size_t)N2*256);
  u16* g0Wih_bf  = wbf;
  u16* g0Whh_bf  = g0Wih_bf + 768*64;
  u16* phi0W_bf  = g0Whh_bf + 768*256;
  u16* g1Wih_bf  = phi0W_bf + 256*384;
  u16* g1Whh_bf  = g1Wih_bf + 768*256;
  u16* phi1W_bf  = g1Whh_bf + 768*256;

  hipMemsetAsync(delta0, 0, (size_t)N1*256*sizeof(float), stream);
  hipMemsetAsync(delta1, 0, (size_t)N2*256*sizeof(float), stream);

  cvt_bf16_kernel<<<192, 256, 0, stream>>>(g0Wih, g0Wih_bf, 768*64);
  cvt_bf16_kernel<<<768, 256, 0, stream>>>(g0Whh, g0Whh_bf, 768*256);
  cvt_bf16_kernel<<<384, 256, 0, stream>>>(phi0W, phi0W_bf, 256*384);
  cvt_bf16_kernel<<<768, 256, 0, stream>>>(g1Wih, g1Wih_bf, 768*256);
  cvt_bf16_kernel<<<768, 256, 0, stream>>>(g1Whh, g1Whh_bf, 768*256);
  cvt_bf16_kernel<<<512, 256, 0, stream>>>(phi1W, phi1W_bf, 256*512);

  const int gN1 = (N1 + 7) / 8;
  const int gN2 = (N2 + 7) / 8;

  // ---- layer 0 ----
  self_slnn_kernel<128, 384><<<gN1, 256, 0, stream>>>(
      N1, nf, nid0, phi0W, phi0b, phi0g, phi0be, nullptr, selfh0, nullptr);

  // TM=64, single-buffered x: LDS 77.3 KB -> 2 blocks/CU
  gru_mfma_kernel<64, 64, 128, 1><<<(E0 + 63) / 64, 512, 0, stream>>>(
      E0, x0, nf, src0, dst0, hist0,
      g0Wih_bf, g0Whh_bf, g0bih, g0bhh,
      phi0W_bf, phi0b, phi0g, phi0be, delta0);

  compose_slnn_kernel<<<gN1, 256, 0, stream>>>(
      N1, delta0, selfh0, selfh0, subg1, nullptr, nullptr,
      nu0W, nu0b, nu0g, nu0be, h1p);

  // ---- layer 1 ----
  self_slnn_kernel<256, 512><<<gN2, 256, 0, stream>>>(
      N2, h1p, nid1, phi1W, phi1b, phi1g, phi1be, hist1, selfh1, selfd1);

  // TM=32, double-buffered x: LDS 67.8 KB -> 2 blocks/CU
  gru_mfma_kernel<32, 256, 256, 2><<<(E1 + 31) / 32, 512, 0, stream>>>(
      E1, x1, h1p, src1, dst1, hist1,
      g1Wih_bf, g1Whh_bf, g1bih, g1bhh,
      phi1W_bf, phi1b, phi1g, phi1be, delta1);

  compose_slnn_kernel<<<gN2, 256, 0, stream>>>(
      N2, delta1, selfd1, selfh1, subg2, aggh1, norm2,
      nu1W, nu1b, nu1g, nu1be, h2p);

  // ---- readout ----
  readout_kernel<<<gN2, 256, 0, stream>>>(
      N2, h2p, fc1W, fc1b, fc2W, fc2b, (float*)d_out);

  (void)n_in; (void)out_size; (void)ws_size;
}

// Round 3
// 2799.860 us; speedup vs baseline: 1.4290x; 1.4290x over previous
//
#include <hip/hip_runtime.h>

typedef unsigned short u16;
typedef __attribute__((ext_vector_type(4))) float f32x4;
typedef __attribute__((ext_vector_type(8))) short bf16x8;
#define MFMA16(a,b,c) __builtin_amdgcn_mfma_f32_16x16x32_bf16((a),(b),(c),0,0,0)

template<int N> struct ic { static constexpr int v = N; };

__device__ __forceinline__ u16 f2bf(float f){
  unsigned int u = __float_as_uint(f);
  u += 0x7FFFu + ((u >> 16) & 1u);
  return (u16)(u >> 16);
}
__device__ __forceinline__ float bf2f(u16 h){
  return __uint_as_float(((unsigned int)h) << 16);
}
__device__ __forceinline__ float sigmoid_f(float x){
  x = fminf(fmaxf(x, -30.f), 30.f);
  return __fdividef(1.f, 1.f + __expf(-x));
}
__device__ __forceinline__ float tanh_f(float x){
  x = fminf(fmaxf(x, -15.f), 15.f);
  float e = __expf(-2.f * x);
  return __fdividef(1.f - e, 1.f + e);
}

// fp32 -> bf16 weight conversion (grid-stride)
__global__ void cvt_bf16_kernel(const float* __restrict__ in, u16* __restrict__ out, int n){
  int i = blockIdx.x * 256 + threadIdx.x;
  int stride = gridDim.x * 256;
  for (; i < n; i += stride) out[i] = f2bf(in[i]);
}

// Block-wide LN stats for R rows of a [R x 256] LDS buffer (stride 256).
template<int R>
__device__ __forceinline__ void ln_stats_rows(const float* __restrict__ O,
                                              float* __restrict__ mean_s,
                                              float* __restrict__ rstd_s){
  const int tid  = threadIdx.x;
  const int wave = tid >> 6, lane = tid & 63;
  constexpr int RW = R / 4;
  #pragma unroll
  for (int rr = 0; rr < RW; rr++){
    const int r = wave * RW + rr;
    float s = 0.f, q = 0.f;
    #pragma unroll
    for (int i = lane; i < 256; i += 64){ float v = O[r*256 + i]; s += v; q += v*v; }
    #pragma unroll
    for (int off = 32; off; off >>= 1){ s += __shfl_down(s, off); q += __shfl_down(q, off); }
    if (lane == 0){
      float m   = s * (1.f/256.f);
      float var = q * (1.f/256.f) - m*m;
      mean_s[r] = m;
      rstd_s[r] = rsqrtf(fmaxf(var, 0.f) + 1e-5f);
    }
  }
}

// ---------------------------------------------------------------------------
// MFMA-based fused per-edge kernel, v4:
//   TM edges/block, 512 threads (8 waves), wave w owns output cols
//   [w*32, w*32+32), processed as two sequential 16-col phases.
//   h double-buffered in LDS.  x tile: XBUFS==2 -> double-buffered (1 barrier
//   per step); XBUFS==1 -> single-buffered (2 barriers/step) to fit
//   LDS <= 80 KB so TWO blocks are resident per CU.
//   __launch_bounds__(512, 2): round-2's (512,4) clamped arch-VGPR to 64 and
//   spilled the 64-reg gate accumulators to scratch (FETCH/WRITE +2 GB each,
//   +40% time). (512,2) lets the allocator land at 128 (round-1 evidence),
//   which still permits 2 blocks/CU (VGPR tier 128 = 16 waves/CU).
// ---------------------------------------------------------------------------
template<int TM, int DIN, int NFD, int XBUFS>
__global__ __launch_bounds__(512, 2)
void gru_mfma_kernel(int E,
    const float* __restrict__ x,        // [E, 8, DIN] fp32
    const float* __restrict__ nodef,    // [*, NFD] fp32
    const int*   __restrict__ src,
    const int*   __restrict__ dst,
    const float* __restrict__ hist,     // [*, 256] fp32
    const u16*   __restrict__ Wih,      // [768, DIN] bf16
    const u16*   __restrict__ Whh,      // [768, 256] bf16
    const float* __restrict__ bih,
    const float* __restrict__ bhh,
    const u16*   __restrict__ phiW,     // [256, NFD+256] bf16
    const float* __restrict__ phib,
    const float* __restrict__ phig,
    const float* __restrict__ phibeta,
    float* __restrict__ delta)          // [*, 256] fp32, pre-zeroed
{
  constexpr int HP   = 264;             // h row stride (+8: 16B-aligned rows)
  constexpr int XP   = DIN + 8;         // x row stride
  constexpr int NP   = NFD + 8;         // nodef row stride
  constexpr int KP   = NFD + 256;       // phi K
  constexpr int MT   = TM / 16;         // m-tiles
  constexpr int NF4  = (TM * DIN) / 2048;  // float4/thread per x stage
  constexpr int HBUF = TM * HP;
  constexpr int XBUF = TM * XP;

  __shared__ __align__(16) u16 hb[2 * HBUF];
  __shared__ __align__(16) u16 xb[XBUFS * XBUF];
  __shared__ int srcs_s[TM], dsts_s[TM];

  const int tid  = threadIdx.x;
  const int wave = tid >> 6, lane = tid & 63;
  const int quad = lane >> 4, ln15 = lane & 15;
  const int qoff = quad * 8;
  const int cbase = wave * 32;
  const int e0   = blockIdx.x * TM;

  if (tid < TM){
    int e  = e0 + tid;
    int ec = (e < E) ? e : (E - 1);
    srcs_s[tid] = src[ec];
    dsts_s[tid] = dst[ec];
  }

  int cn[2]; float brc[2], bzc[2], bnic[2], bnhc[2], pb[2], gg[2], gb[2];
  #pragma unroll
  for (int nt = 0; nt < 2; nt++){
    int c   = cbase + nt * 16 + ln15;
    cn[nt]  = c;
    brc[nt]  = bih[c]       + bhh[c];
    bzc[nt]  = bih[256 + c] + bhh[256 + c];
    bnic[nt] = bih[512 + c];
    bnhc[nt] = bhh[512 + c];
    pb[nt]   = phib[c];
    gg[nt]   = phig[c];
    gb[nt]   = phibeta[c];
  }

  // stage x_0 into buffer 0
  #pragma unroll
  for (int j = 0; j < NF4; j++){
    int i4 = tid + j * 512;
    int e  = i4 / (DIN / 4);
    int k4 = (i4 % (DIN / 4)) * 4;
    int ge = (e0 + e < E) ? (e0 + e) : (E - 1);
    float4 v = *(const float4*)(x + (size_t)ge * (8 * DIN) + k4);
    ushort4 u;
    u.x = f2bf(v.x); u.y = f2bf(v.y); u.z = f2bf(v.z); u.w = f2bf(v.w);
    *(ushort4*)(xb + e * XP + k4) = u;
  }
  __syncthreads();

  float hs[2][MT][4];
  #pragma unroll
  for (int nt = 0; nt < 2; nt++)
    #pragma unroll
    for (int mt = 0; mt < MT; mt++)
      #pragma unroll
      for (int q = 0; q < 4; q++) hs[nt][mt][q] = 0.f;

  const f32x4 zero4 = {0.f, 0.f, 0.f, 0.f};

  #pragma unroll 1
  for (int t = 0; t < 8; t++){
    const u16* rd = hb + ((t & 1) ^ 1) * HBUF;
    u16*       wr = hb + (t & 1) * HBUF;
    const u16* xr = xb + ((XBUFS == 2) ? (t & 1) * XBUF : 0);

    // prefetch x_{t+1} into registers (HBM latency hidden under this step)
    float4 xpre[NF4];
    if (t < 7){
      #pragma unroll
      for (int j = 0; j < NF4; j++){
        int i4 = tid + j * 512;
        int e  = i4 / (DIN / 4);
        int k4 = (i4 % (DIN / 4)) * 4;
        int ge = (e0 + e < E) ? (e0 + e) : (E - 1);
        xpre[j] = *(const float4*)(x + (size_t)ge * (8 * DIN) + (size_t)(t + 1) * DIN + k4);
      }
    }

    auto phase = [&](auto ntc){
      constexpr int NT = decltype(ntc)::v;    // compile-time phase: static idx
      const int c = cn[NT];
      f32x4 aR[MT], aZ[MT], aNI[MT], aNH[MT];
      #pragma unroll
      for (int mt = 0; mt < MT; mt++){
        aR[mt] = zero4; aZ[mt] = zero4; aNI[mt] = zero4; aNH[mt] = zero4;
      }
      if (t > 0){
        #pragma unroll
        for (int kt = 0; kt < 8; kt++){
          bf16x8 a[MT];
          #pragma unroll
          for (int mt = 0; mt < MT; mt++)
            a[mt] = *(const bf16x8*)(rd + (mt*16 + ln15) * HP + kt * 32 + qoff);
          const u16* bp = Whh + (size_t)c * 256 + kt * 32 + qoff;
          bf16x8 br = *(const bf16x8*)(bp);
          bf16x8 bz = *(const bf16x8*)(bp + 256 * 256);
          bf16x8 bn = *(const bf16x8*)(bp + 512 * 256);
          #pragma unroll
          for (int mt = 0; mt < MT; mt++){
            aR[mt]  = MFMA16(a[mt], br, aR[mt]);
            aZ[mt]  = MFMA16(a[mt], bz, aZ[mt]);
            aNH[mt] = MFMA16(a[mt], bn, aNH[mt]);
          }
        }
      }
      #pragma unroll
      for (int kt = 0; kt < DIN / 32; kt++){
        bf16x8 a[MT];
        #pragma unroll
        for (int mt = 0; mt < MT; mt++)
          a[mt] = *(const bf16x8*)(xr + (mt*16 + ln15) * XP + kt * 32 + qoff);
        const u16* bp = Wih + (size_t)c * DIN + kt * 32 + qoff;
        bf16x8 br = *(const bf16x8*)(bp);
        bf16x8 bz = *(const bf16x8*)(bp + 256 * DIN);
        bf16x8 bn = *(const bf16x8*)(bp + 512 * DIN);
        #pragma unroll
        for (int mt = 0; mt < MT; mt++){
          aR[mt]  = MFMA16(a[mt], br, aR[mt]);
          aZ[mt]  = MFMA16(a[mt], bz, aZ[mt]);
          aNI[mt] = MFMA16(a[mt], bn, aNI[mt]);
        }
      }
      // gates + h update (own 16 cols of this phase)
      #pragma unroll
      for (int mt = 0; mt < MT; mt++){
        #pragma unroll
        for (int q = 0; q < 4; q++){
          const int e = mt * 16 + quad * 4 + q;
          float r = sigmoid_f(aR[mt][q] + brc[NT]);
          float z = sigmoid_f(aZ[mt][q] + bzc[NT]);
          float n = tanh_f(aNI[mt][q] + bnic[NT] + r * (aNH[mt][q] + bnhc[NT]));
          float hold = (t > 0) ? bf2f(rd[e * HP + c]) : 0.f;
          float hnew = (1.f - z) * n + z * hold;
          hs[NT][mt][q] += hnew;
          if (t < 7) wr[e * HP + c] = f2bf(hnew);
        }
      }
    };
    phase(ic<0>());
    phase(ic<1>());

    if (XBUFS == 1){
      __syncthreads();                       // all x_t / h reads done
      if (t < 7){
        #pragma unroll
        for (int j = 0; j < NF4; j++){
          int i4 = tid + j * 512;
          int e  = i4 / (DIN / 4);
          int k4 = (i4 % (DIN / 4)) * 4;
          ushort4 u;
          u.x = f2bf(xpre[j].x); u.y = f2bf(xpre[j].y);
          u.z = f2bf(xpre[j].z); u.w = f2bf(xpre[j].w);
          *(ushort4*)(xb + e * XP + k4) = u;
        }
        __syncthreads();                     // x_{t+1} visible
      }
    } else {
      if (t < 7){
        u16* xw = xb + (((t + 1) & 1)) * XBUF;
        #pragma unroll
        for (int j = 0; j < NF4; j++){
          int i4 = tid + j * 512;
          int e  = i4 / (DIN / 4);
          int k4 = (i4 % (DIN / 4)) * 4;
          ushort4 u;
          u.x = f2bf(xpre[j].x); u.y = f2bf(xpre[j].y);
          u.z = f2bf(xpre[j].z); u.w = f2bf(xpre[j].w);
          *(ushort4*)(xw + e * XP + k4) = u;
        }
      }
      __syncthreads();
    }
  }

  // emb = mean(h) -> hb buf0; stage nodef[src] into free LDS:
  //   XBUFS==1: h buf1 (dead since t=6); XBUFS==2: xb buf0 (dead since t=6).
  u16* nb = (XBUFS == 1) ? (hb + HBUF) : xb;
  {
    u16* eb = hb;
    #pragma unroll
    for (int nt = 0; nt < 2; nt++)
      #pragma unroll
      for (int mt = 0; mt < MT; mt++)
        #pragma unroll
        for (int q = 0; q < 4; q++){
          const int e = mt * 16 + quad * 4 + q;
          eb[e * HP + cn[nt]] = f2bf(hs[nt][mt][q] * 0.125f);
        }
    constexpr int R4 = NFD / 4;
    for (int i = tid; i < TM * R4; i += 512){
      int e  = i / R4;
      int k4 = (i - e * R4) * 4;
      const float4 v = *(const float4*)(nodef + (size_t)srcs_s[e] * NFD + k4);
      ushort4 u;
      u.x = f2bf(v.x); u.y = f2bf(v.y); u.z = f2bf(v.z); u.w = f2bf(v.w);
      *(ushort4*)(nb + e * NP + k4) = u;
    }
  }
  __syncthreads();

  // phi GEMM: K = NFD (nb) + 256 (emb in hb buf0)
  f32x4 P[2][MT];
  #pragma unroll
  for (int nt = 0; nt < 2; nt++)
    #pragma unroll
    for (int mt = 0; mt < MT; mt++) P[nt][mt] = zero4;

  #pragma unroll
  for (int kt = 0; kt < NFD / 32; kt++){
    bf16x8 a[MT];
    #pragma unroll
    for (int mt = 0; mt < MT; mt++)
      a[mt] = *(const bf16x8*)(nb + (mt*16 + ln15) * NP + kt * 32 + qoff);
    #pragma unroll
    for (int nt = 0; nt < 2; nt++){
      const u16* bp = phiW + (size_t)cn[nt] * KP + kt * 32 + qoff;
      bf16x8 b = *(const bf16x8*)(bp);
      #pragma unroll
      for (int mt = 0; mt < MT; mt++) P[nt][mt] = MFMA16(a[mt], b, P[nt][mt]);
    }
  }
  #pragma unroll
  for (int kt = 0; kt < 8; kt++){
    bf16x8 a[MT];
    #pragma unroll
    for (int mt = 0; mt < MT; mt++)
      a[mt] = *(const bf16x8*)(hb + (mt*16 + ln15) * HP + kt * 32 + qoff);
    #pragma unroll
    for (int nt = 0; nt < 2; nt++){
      const u16* bp = phiW + (size_t)cn[nt] * KP + NFD + kt * 32 + qoff;
      bf16x8 b = *(const bf16x8*)(bp);
      #pragma unroll
      for (int mt = 0; mt < MT; mt++) P[nt][mt] = MFMA16(a[mt], b, P[nt][mt]);
    }
  }

  // LN scratch aliases LDS that is dead in the epilogue:
  //   XBUFS==1: xb (phi reads hb only); XBUFS==2: hb buf1.
  float* sums_s = (float*)((XBUFS == 1) ? (void*)xb : (void*)(hb + HBUF));
  float* sqs_s  = sums_s + 8 * TM;
  float* mean_s = sqs_s  + 8 * TM;
  float* rstd_s = mean_s + TM;

  // bias + LN stats: shuffle over 16 lanes (32 cols/wave) -> cross-wave via LDS
  float sl[MT][4], sq_[MT][4];
  #pragma unroll
  for (int mt = 0; mt < MT; mt++)
    #pragma unroll
    for (int q = 0; q < 4; q++){
      float v0 = P[0][mt][q] + pb[0];
      float v1 = P[1][mt][q] + pb[1];
      P[0][mt][q] = v0; P[1][mt][q] = v1;
      sl[mt][q]  = v0 + v1;
      sq_[mt][q] = v0 * v0 + v1 * v1;
    }
  #pragma unroll
  for (int off = 1; off < 16; off <<= 1){
    #pragma unroll
    for (int mt = 0; mt < MT; mt++)
      #pragma unroll
      for (int q = 0; q < 4; q++){
        sl[mt][q]  += __shfl_xor(sl[mt][q], off);
        sq_[mt][q] += __shfl_xor(sq_[mt][q], off);
      }
  }
  if (ln15 == 0){
    #pragma unroll
    for (int mt = 0; mt < MT; mt++)
      #pragma unroll
      for (int q = 0; q < 4; q++){
        int row = mt * 16 + quad * 4 + q;
        sums_s[wave * TM + row] = sl[mt][q];
        sqs_s[wave * TM + row]  = sq_[mt][q];
      }
  }
  __syncthreads();
  if (tid < TM){
    float m = 0.f, qq = 0.f;
    #pragma unroll
    for (int w = 0; w < 8; w++){ m += sums_s[w * TM + tid]; qq += sqs_s[w * TM + tid]; }
    m  *= (1.f / 256.f);
    qq *= (1.f / 256.f);
    mean_s[tid] = m;
    rstd_s[tid] = rsqrtf(fmaxf(qq - m * m, 0.f) + 1e-5f);
  }
  __syncthreads();

  // y = relu(LN(...)), msg = relu(y - hist[src]) -> atomic scatter into delta[dst]
  #pragma unroll
  for (int nt = 0; nt < 2; nt++){
    const int c = cn[nt];
    #pragma unroll
    for (int mt = 0; mt < MT; mt++)
      #pragma unroll
      for (int q = 0; q < 4; q++){
        const int e  = mt * 16 + quad * 4 + q;
        const int ge = e0 + e;
        float y = (P[nt][mt][q] - mean_s[e]) * rstd_s[e] * gg[nt] + gb[nt];
        y = fmaxf(y, 0.f);
        float mv = y - hist[(size_t)srcs_s[e] * 256 + c];
        if (ge < E && mv > 0.f)
          atomicAdd(delta + (size_t)dsts_s[e] * 256 + c, mv);
      }
  }
}

// ---------------------------------------------------------------------------
// self-SLNN: out = relu(LN(feat[nid] @ W[:, WS-K:].T + b)); optional
// out2 = out - hist[nid].
// ---------------------------------------------------------------------------
template<int K, int WS>
__global__ __launch_bounds__(256)
void self_slnn_kernel(int N,
    const float* __restrict__ feat,
    const int*   __restrict__ nid,
    const float* __restrict__ W,
    const float* __restrict__ b,
    const float* __restrict__ g,
    const float* __restrict__ beta,
    const float* __restrict__ hist,
    float* __restrict__ out,
    float* __restrict__ out2)
{
  constexpr int R = 8;
  __shared__ float X[R*K];
  __shared__ float O[R*256];
  __shared__ float mean_s[R], rstd_s[R];
  __shared__ int   nids[R];
  const int tid = threadIdx.x;
  const int n0  = blockIdx.x * R;
  if (tid < R) nids[tid] = (n0 + tid < N) ? nid[n0 + tid] : 0;
  __syncthreads();
  for (int i = tid; i < R*K; i += 256){
    int r = i / K, k = i - r*K;
    X[i] = feat[(size_t)nids[r]*K + k];
  }
  __syncthreads();
  const int c = tid;
  const float* Wc = W + (size_t)c*WS + (WS - K);
  float acc[R];
  const float bc0 = b[c];
  #pragma unroll
  for (int r = 0; r < R; r++) acc[r] = bc0;
  #pragma unroll 1
  for (int k = 0; k < K; k += 4){
    float4 w = *(const float4*)(Wc + k);
    #pragma unroll
    for (int r = 0; r < R; r++){
      float4 xv = *(const float4*)(X + r*K + k);
      acc[r] += w.x*xv.x + w.y*xv.y + w.z*xv.z + w.w*xv.w;
    }
  }
  #pragma unroll
  for (int r = 0; r < R; r++) O[r*256 + c] = acc[r];
  __syncthreads();
  ln_stats_rows<R>(O, mean_s, rstd_s);
  __syncthreads();
  const float gc = g[c], bc = beta[c];
  #pragma unroll
  for (int r = 0; r < R; r++){
    int n = n0 + r;
    if (n < N){
      float y = fmaxf((acc[r] - mean_s[r]) * rstd_s[r] * gc + bc, 0.f);
      out[(size_t)n*256 + c] = y;
      if (out2) out2[(size_t)n*256 + c] = y - hist[(size_t)nids[r]*256 + c];
    }
  }
}

// ---------------------------------------------------------------------------
// compose-SLNN: X = [ (delta - selfA)*subg (+ agg*normv) | selfB ]  (K=512)
// ---------------------------------------------------------------------------
__global__ __launch_bounds__(256)
void compose_slnn_kernel(int N,
    const float* __restrict__ delta,
    const float* __restrict__ selfA,
    const float* __restrict__ selfB,
    const float* __restrict__ subg,
    const float* __restrict__ agg,
    const float* __restrict__ normv,
    const float* __restrict__ W,     // [256, 512]
    const float* __restrict__ b,
    const float* __restrict__ g,
    const float* __restrict__ beta,
    float* __restrict__ out)
{
  constexpr int R = 8;
  __shared__ float X[R*512];
  __shared__ float O[R*256];
  __shared__ float mean_s[R], rstd_s[R];
  const int tid = threadIdx.x;
  const int n0  = blockIdx.x * R;
  for (int i = tid; i < R*512; i += 256){
    int r = i >> 9, k = i & 511;
    int n = n0 + r;
    float v = 0.f;
    if (n < N){
      if (k < 256){
        v = (delta[(size_t)n*256 + k] - selfA[(size_t)n*256 + k]) * subg[n];
        if (agg) v += agg[(size_t)n*256 + k] * normv[n];
      } else {
        v = selfB[(size_t)n*256 + (k - 256)];
      }
    }
    X[i] = v;
  }
  __syncthreads();
  const int c = tid;
  const float* Wc = W + (size_t)c*512;
  float acc[R];
  const float bc0 = b[c];
  #pragma unroll
  for (int r = 0; r < R; r++) acc[r] = bc0;
  #pragma unroll 1
  for (int k = 0; k < 512; k += 4){
    float4 w = *(const float4*)(Wc + k);
    #pragma unroll
    for (int r = 0; r < R; r++){
      float4 xv = *(const float4*)(X + r*512 + k);
      acc[r] += w.x*xv.x + w.y*xv.y + w.z*xv.z + w.w*xv.w;
    }
  }
  #pragma unroll
  for (int r = 0; r < R; r++) O[r*256 + c] = acc[r];
  __syncthreads();
  ln_stats_rows<R>(O, mean_s, rstd_s);
  __syncthreads();
  const float gc = g[c], bc = beta[c];
  #pragma unroll
  for (int r = 0; r < R; r++){
    int n = n0 + r;
    if (n < N)
      out[(size_t)n*256 + c] = fmaxf((acc[r] - mean_s[r]) * rstd_s[r] * gc + bc, 0.f);
  }
}

// ---------------------------------------------------------------------------
// readout: logit = (h2 @ fc1.T + b1) @ fc2.T + b2
// ---------------------------------------------------------------------------
__global__ __launch_bounds__(256)
void readout_kernel(int N,
    const float* __restrict__ h2,
    const float* __restrict__ W1,  // [512, 256]
    const float* __restrict__ b1,
    const float* __restrict__ W2,  // [16, 512]
    const float* __restrict__ b2,
    float* __restrict__ out)
{
  constexpr int R = 8;
  __shared__ float X[R*256];
  __shared__ float T[R*512];
  const int tid = threadIdx.x;
  const int n0  = blockIdx.x * R;
  for (int i = tid; i < R*256; i += 256){
    int r = i >> 8, k = i & 255;
    int n = n0 + r;
    X[i] = (n < N) ? h2[(size_t)n*256 + k] : 0.f;
  }
  __syncthreads();
  const int c = tid;
  const float* Wa = W1 + (size_t)c*256;
  const float* Wb = W1 + (size_t)(c+256)*256;
  float acca[R], accb[R];
  const float ba = b1[c], bb = b1[c+256];
  #pragma unroll
  for (int r = 0; r < R; r++){ acca[r] = ba; accb[r] = bb; }
  #pragma unroll 1
  for (int k = 0; k < 256; k += 4){
    float4 wa = *(const float4*)(Wa + k);
    float4 wb = *(const float4*)(Wb + k);
    #pragma unroll
    for (int r = 0; r < R; r++){
      float4 xv = *(const float4*)(X + r*256 + k);
      acca[r] += wa.x*xv.x + wa.y*xv.y + wa.z*xv.z + wa.w*xv.w;
      accb[r] += wb.x*xv.x + wb.y*xv.y + wb.z*xv.z + wb.w*xv.w;
    }
  }
  #pragma unroll
  for (int r = 0; r < R; r++){ T[r*512 + c] = acca[r]; T[r*512 + 256 + c] = accb[r]; }
  __syncthreads();
  if (tid < R*16){
    int r = tid >> 4, o = tid & 15;
    int n = n0 + r;
    if (n < N){
      float s = b2[o];
      const float* w  = W2 + (size_t)o*512;
      const float* tr = T + r*512;
      #pragma unroll 4
      for (int k = 0; k < 512; k++) s += tr[k]*w[k];
      out[(size_t)n*16 + o] = s;
    }
  }
}

// ---------------------------------------------------------------------------
extern "C" void kernel_launch(void* const* d_in, const int* in_sizes, int n_in,
                              void* d_out, int out_size, void* d_ws, size_t ws_size,
                              hipStream_t stream) {
  const float* nf     = (const float*)d_in[0];
  const float* x0     = (const float*)d_in[1];
  const float* x1     = (const float*)d_in[2];
  const float* hist0  = (const float*)d_in[3];
  const float* hist1  = (const float*)d_in[4];
  const float* aggh1  = (const float*)d_in[5];
  const float* subg1  = (const float*)d_in[6];
  const float* subg2  = (const float*)d_in[7];
  const float* norm2  = (const float*)d_in[8];
  const int*   src0   = (const int*)d_in[9];
  const int*   dst0   = (const int*)d_in[10];
  const int*   src1   = (const int*)d_in[11];
  const int*   dst1   = (const int*)d_in[12];
  const int*   nid0   = (const int*)d_in[13];
  const int*   nid1   = (const int*)d_in[14];
  const float* g0Wih  = (const float*)d_in[15];
  const float* g0Whh  = (const float*)d_in[16];
  const float* g0bih  = (const float*)d_in[17];
  const float* g0bhh  = (const float*)d_in[18];
  const float* g1Wih  = (const float*)d_in[19];
  const float* g1Whh  = (const float*)d_in[20];
  const float* g1bih  = (const float*)d_in[21];
  const float* g1bhh  = (const float*)d_in[22];
  const float* phi0W  = (const float*)d_in[23];
  const float* phi0b  = (const float*)d_in[24];
  const float* phi0g  = (const float*)d_in[25];
  const float* phi0be = (const float*)d_in[26];
  const float* phi1W  = (const float*)d_in[27];
  const float* phi1b  = (const float*)d_in[28];
  const float* phi1g  = (const float*)d_in[29];
  const float* phi1be = (const float*)d_in[30];
  const float* nu0W   = (const float*)d_in[31];
  const float* nu0b   = (const float*)d_in[32];
  const float* nu0g   = (const float*)d_in[33];
  const float* nu0be  = (const float*)d_in[34];
  const float* nu1W   = (const float*)d_in[35];
  const float* nu1b   = (const float*)d_in[36];
  const float* nu1g   = (const float*)d_in[37];
  const float* nu1be  = (const float*)d_in[38];
  const float* fc1W   = (const float*)d_in[39];
  const float* fc1b   = (const float*)d_in[40];
  const float* fc2W   = (const float*)d_in[41];
  const float* fc2b   = (const float*)d_in[42];

  const int E0 = in_sizes[9];
  const int E1 = in_sizes[11];
  const int N1 = in_sizes[13];
  const int N2 = in_sizes[14];

  float* ws     = (float*)d_ws;
  float* delta0 = ws;
  float* selfh0 = delta0 + (size_t)N1*256;
  float* h1p    = selfh0 + (size_t)N1*256;
  float* delta1 = h1p    + (size_t)N1*256;
  float* selfh1 = delta1 + (size_t)N2*256;
  float* selfd1 = selfh1 + (size_t)N2*256;
  float* h2p    = selfd1 + (size_t)N2*256;

  // bf16 weight copies (converted every call; ws is re-poisoned by harness)
  u16* wbf       = (u16*)(h2p + (size_t)N2*256);
  u16* g0Wih_bf  = wbf;
  u16* g0Whh_bf  = g0Wih_bf + 768*64;
  u16* phi0W_bf  = g0Whh_bf + 768*256;
  u16* g1Wih_bf  = phi0W_bf + 256*384;
  u16* g1Whh_bf  = g1Wih_bf + 768*256;
  u16* phi1W_bf  = g1Whh_bf + 768*256;

  hipMemsetAsync(delta0, 0, (size_t)N1*256*sizeof(float), stream);
  hipMemsetAsync(delta1, 0, (size_t)N2*256*sizeof(float), stream);

  cvt_bf16_kernel<<<192, 256, 0, stream>>>(g0Wih, g0Wih_bf, 768*64);
  cvt_bf16_kernel<<<768, 256, 0, stream>>>(g0Whh, g0Whh_bf, 768*256);
  cvt_bf16_kernel<<<384, 256, 0, stream>>>(phi0W, phi0W_bf, 256*384);
  cvt_bf16_kernel<<<768, 256, 0, stream>>>(g1Wih, g1Wih_bf, 768*256);
  cvt_bf16_kernel<<<768, 256, 0, stream>>>(g1Whh, g1Whh_bf, 768*256);
  cvt_bf16_kernel<<<512, 256, 0, stream>>>(phi1W, phi1W_bf, 256*512);

  const int gN1 = (N1 + 7) / 8;
  const int gN2 = (N2 + 7) / 8;

  // ---- layer 0 ----
  self_slnn_kernel<128, 384><<<gN1, 256, 0, stream>>>(
      N1, nf, nid0, phi0W, phi0b, phi0g, phi0be, nullptr, selfh0, nullptr);

  // TM=64, single-buffered x: LDS 77.3 KB -> 2 blocks/CU (VGPR <= 128)
  gru_mfma_kernel<64, 64, 128, 1><<<(E0 + 63) / 64, 512, 0, stream>>>(
      E0, x0, nf, src0, dst0, hist0,
      g0Wih_bf, g0Whh_bf, g0bih, g0bhh,
      phi0W_bf, phi0b, phi0g, phi0be, delta0);

  compose_slnn_kernel<<<gN1, 256, 0, stream>>>(
      N1, delta0, selfh0, selfh0, subg1, nullptr, nullptr,
      nu0W, nu0b, nu0g, nu0be, h1p);

  // ---- layer 1 ----
  self_slnn_kernel<256, 512><<<gN2, 256, 0, stream>>>(
      N2, h1p, nid1, phi1W, phi1b, phi1g, phi1be, hist1, selfh1, selfd1);

  // TM=32, double-buffered x: LDS 67.8 KB -> 2 blocks/CU
  gru_mfma_kernel<32, 256, 256, 2><<<(E1 + 31) / 32, 512, 0, stream>>>(
      E1, x1, h1p, src1, dst1, hist1,
      g1Wih_bf, g1Whh_bf, g1bih, g1bhh,
      phi1W_bf, phi1b, phi1g, phi1be, delta1);

  compose_slnn_kernel<<<gN2, 256, 0, stream>>>(
      N2, delta1, selfd1, selfh1, subg2, aggh1, norm2,
      nu1W, nu1b, nu1g, nu1be, h2p);

  // ---- readout ----
  readout_kernel<<<gN2, 256, 0, stream>>>(
      N2, h2p, fc1W, fc1b, fc2W, fc2b, (float*)d_out);

  (void)n_in; (void)out_size; (void)ws_size;
}